// Round 1
// baseline (332.014 us; speedup 1.0000x reference)
//
#include <hip/hip_runtime.h>

#define HEADS 8
#define Bq 4
#define Nq 2048
#define Dq 512
#define Hq 2048

typedef __bf16 bf16;
typedef __bf16 bf16x8 __attribute__((ext_vector_type(8)));
typedef float f32x4 __attribute__((ext_vector_type(4)));

// ---------------- fp32 -> bf16 elementwise convert ----------------
__global__ __launch_bounds__(256) void k_cvt_bf16(const float* __restrict__ in,
                                                  bf16* __restrict__ out, int n) {
  int i = (blockIdx.x * 256 + threadIdx.x) * 4;
  if (i >= n) return;
  float4 v = *(const float4*)(in + i);
  union { bf16 h[4]; ushort4 u; } r;
  r.h[0] = (bf16)v.x; r.h[1] = (bf16)v.y; r.h[2] = (bf16)v.z; r.h[3] = (bf16)v.w;
  *(ushort4*)(out + i) = r.u;
}

// ---------------- transpose + convert: in fp32 [K][N] -> out bf16 [N][K] ----------------
__global__ __launch_bounds__(256) void k_transpose_cvt(const float* __restrict__ in,
                                                       bf16* __restrict__ out,
                                                       int K, int N) {
  __shared__ float t[32][33];
  const int n0 = blockIdx.x * 32, k0 = blockIdx.y * 32;
  const int tx = threadIdx.x, ty = threadIdx.y;
#pragma unroll
  for (int j = 0; j < 32; j += 8)
    t[ty + j][tx] = in[(size_t)(k0 + ty + j) * N + n0 + tx];
  __syncthreads();
#pragma unroll
  for (int j = 0; j < 32; j += 8)
    out[(size_t)(n0 + ty + j) * K + k0 + tx] = (bf16)t[tx][ty + j];
}

// ---------------- GEMM: C[M][N] = A[M][K](bf16) * BT[N][K]^T(bf16) + bias, epilogues ----------------
// 128x128 tile, BK=32, 256 threads = 4 waves in 2x2. mfma_f32_16x16x32_bf16.
template <bool GELU, bool RESID, bool STORE_BF16>
__global__ __launch_bounds__(256) void k_gemm(const bf16* __restrict__ A,
                                              const bf16* __restrict__ BT,
                                              const float* __restrict__ bias,
                                              const float* __restrict__ resid,
                                              void* __restrict__ Cout,
                                              int M, int N, int K) {
  __shared__ bf16 As[128 * 40];  // +8 pad: row stride 80B (16B-aligned, 2-way banks)
  __shared__ bf16 Bs[128 * 40];
  const int m0 = blockIdx.y * 128, n0 = blockIdx.x * 128;
  const int tid = threadIdx.x, lane = tid & 63, wid = tid >> 6;
  const int wr = wid >> 1, wc = wid & 1;
  const int r16 = lane & 15, g = lane >> 4;

  f32x4 acc[4][4] = {};

  for (int k0 = 0; k0 < K; k0 += 32) {
    __syncthreads();
#pragma unroll
    for (int i = 0; i < 2; i++) {
      int c = tid + i * 256;          // 0..511
      int row = c >> 2, kc = c & 3;   // 128 rows x 4 chunks of 8 bf16
      *(int4*)(As + row * 40 + kc * 8) =
          *(const int4*)(A + (size_t)(m0 + row) * K + k0 + kc * 8);
      *(int4*)(Bs + row * 40 + kc * 8) =
          *(const int4*)(BT + (size_t)(n0 + row) * K + k0 + kc * 8);
    }
    __syncthreads();

    bf16x8 af[4], bfr[4];
#pragma unroll
    for (int mi = 0; mi < 4; mi++)
      af[mi] = *(const bf16x8*)(As + (wr * 64 + mi * 16 + r16) * 40 + g * 8);
#pragma unroll
    for (int ni = 0; ni < 4; ni++)
      bfr[ni] = *(const bf16x8*)(Bs + (wc * 64 + ni * 16 + r16) * 40 + g * 8);
#pragma unroll
    for (int mi = 0; mi < 4; mi++)
#pragma unroll
      for (int ni = 0; ni < 4; ni++)
        acc[mi][ni] = __builtin_amdgcn_mfma_f32_16x16x32_bf16(af[mi], bfr[ni],
                                                              acc[mi][ni], 0, 0, 0);
  }

#pragma unroll
  for (int mi = 0; mi < 4; mi++)
#pragma unroll
    for (int ni = 0; ni < 4; ni++) {
      int col = n0 + wc * 64 + ni * 16 + r16;
      float bv = bias[col];
#pragma unroll
      for (int r = 0; r < 4; r++) {
        int row = m0 + wr * 64 + mi * 16 + 4 * g + r;
        float v = acc[mi][ni][r] + bv;
        if (GELU) v = 0.5f * v * (1.f + erff(v * 0.70710678118654752f));
        if (RESID) v += resid[(size_t)row * N + col];
        if (STORE_BF16) ((bf16*)Cout)[(size_t)row * N + col] = (bf16)v;
        else            ((float*)Cout)[(size_t)row * N + col] = v;
      }
    }
}

// ---------------- flash attention: qkv bf16 [B*N][1536] -> att bf16 [B*N][512] ----------------
// grid (N/128, B*HEADS), 256 thr = 4 waves, each wave 32 q-rows; KVBLK=64.
// reference: softmax(QK^T) * 0.125 then @V  -> fold 0.125 into final normalize.
__global__ __launch_bounds__(256) void k_attn(const bf16* __restrict__ qkv,
                                              bf16* __restrict__ att) {
  __shared__ bf16 Ks[64 * 72];       // K-tile natural [kv][e], pad 72
  __shared__ bf16 VT[64 * 72];       // V-tile transposed [e][kv], pad 72
  __shared__ bf16 Ps[4][32 * 72];    // per-wave P scratch [row][kv], pad 72
  const int qt = blockIdx.x, b = blockIdx.y >> 3, h = blockIdx.y & 7;
  const int tid = threadIdx.x, lane = tid & 63, wid = tid >> 6;
  const int r16 = lane & 15, g = lane >> 4;
  const size_t base = (size_t)b * Nq * (3 * Dq);
  const bf16* qp = qkv + base + h * 64;
  const bf16* kp = qkv + base + Dq + h * 64;
  const bf16* vp = qkv + base + 2 * Dq + h * 64;
  const int q0 = qt * 128 + wid * 32;

  // Q fragments: [mi][k-slab of 32]
  bf16x8 qf[2][2];
#pragma unroll
  for (int mi = 0; mi < 2; mi++)
#pragma unroll
    for (int kk = 0; kk < 2; kk++)
      qf[mi][kk] = *(const bf16x8*)(qp + (size_t)(q0 + mi * 16 + r16) * (3 * Dq) +
                                    kk * 32 + g * 8);

  f32x4 o[2][4] = {};
  float mrow[2][4], lrow[2][4];
#pragma unroll
  for (int mi = 0; mi < 2; mi++)
#pragma unroll
    for (int r = 0; r < 4; r++) { mrow[mi][r] = -INFINITY; lrow[mi][r] = 0.f; }

  for (int kv0 = 0; kv0 < Nq; kv0 += 64) {
    __syncthreads();
#pragma unroll
    for (int i = 0; i < 2; i++) {
      int c = tid + i * 256;             // 0..511
      int kvr = c >> 3, ec = c & 7;      // 64 rows x 8 chunks
      *(int4*)(Ks + kvr * 72 + ec * 8) =
          *(const int4*)(kp + (size_t)(kv0 + kvr) * (3 * Dq) + ec * 8);
      bf16x8 vv = *(const bf16x8*)(vp + (size_t)(kv0 + kvr) * (3 * Dq) + ec * 8);
#pragma unroll
      for (int j = 0; j < 8; j++) VT[(ec * 8 + j) * 72 + kvr] = vv[j];
    }
    __syncthreads();

    // S = Q @ K^T  (s-tile C-layout: row=4g+reg, col=r16)
    f32x4 s[2][4] = {};
#pragma unroll
    for (int nt = 0; nt < 4; nt++)
#pragma unroll
      for (int kk = 0; kk < 2; kk++) {
        bf16x8 kf = *(const bf16x8*)(Ks + (nt * 16 + r16) * 72 + kk * 32 + g * 8);
#pragma unroll
        for (int mi = 0; mi < 2; mi++)
          s[mi][nt] = __builtin_amdgcn_mfma_f32_16x16x32_bf16(qf[mi][kk], kf,
                                                              s[mi][nt], 0, 0, 0);
      }

    // online softmax per row (this lane owns rows 4g+r of each 16-tile)
#pragma unroll
    for (int mi = 0; mi < 2; mi++)
#pragma unroll
      for (int r = 0; r < 4; r++) {
        float mx = fmaxf(fmaxf(s[mi][0][r], s[mi][1][r]),
                         fmaxf(s[mi][2][r], s[mi][3][r]));
#pragma unroll
        for (int off = 1; off < 16; off <<= 1) mx = fmaxf(mx, __shfl_xor(mx, off));
        float mold = mrow[mi][r];
        float mnew = fmaxf(mold, mx);
        float scale = __expf(mold - mnew);
        mrow[mi][r] = mnew;
        float rs = 0.f;
#pragma unroll
        for (int nt = 0; nt < 4; nt++) {
          float pv = __expf(s[mi][nt][r] - mnew);
          s[mi][nt][r] = pv;
          rs += pv;
        }
#pragma unroll
        for (int off = 1; off < 16; off <<= 1) rs += __shfl_xor(rs, off);
        lrow[mi][r] = lrow[mi][r] * scale + rs;
#pragma unroll
        for (int ot = 0; ot < 4; ot++) o[mi][ot][r] *= scale;
#pragma unroll
        for (int nt = 0; nt < 4; nt++)
          Ps[wid][(mi * 16 + 4 * g + r) * 72 + nt * 16 + r16] = (bf16)s[mi][nt][r];
      }

    // O += P @ V   (A-frag from Ps, B-frag from VT)
#pragma unroll
    for (int ot = 0; ot < 4; ot++)
#pragma unroll
      for (int kk = 0; kk < 2; kk++) {
        bf16x8 vf = *(const bf16x8*)(VT + (ot * 16 + r16) * 72 + kk * 32 + g * 8);
#pragma unroll
        for (int mi = 0; mi < 2; mi++) {
          bf16x8 pf = *(const bf16x8*)(Ps[wid] + (mi * 16 + r16) * 72 + kk * 32 + g * 8);
          o[mi][ot] = __builtin_amdgcn_mfma_f32_16x16x32_bf16(pf, vf, o[mi][ot], 0, 0, 0);
        }
      }
  }

#pragma unroll
  for (int mi = 0; mi < 2; mi++)
#pragma unroll
    for (int ot = 0; ot < 4; ot++)
#pragma unroll
      for (int r = 0; r < 4; r++) {
        int row = q0 + mi * 16 + 4 * g + r;
        int col = h * 64 + ot * 16 + r16;
        att[((size_t)b * Nq + row) * Dq + col] =
            (bf16)(o[mi][ot][r] * 0.125f / lrow[mi][r]);
      }
}

// ---------------- LayerNorm over D=512, one wave per row ----------------
template <bool WB>
__global__ __launch_bounds__(64) void k_ln(const float* __restrict__ in,
                                           const float* __restrict__ gamma,
                                           const float* __restrict__ beta,
                                           float* __restrict__ outf,
                                           bf16* __restrict__ outb) {
  const int row = blockIdx.x, lane = threadIdx.x;
  const float* p = in + (size_t)row * Dq + lane * 8;
  float4 a = *(const float4*)p;
  float4 c = *(const float4*)(p + 4);
  float vals[8] = {a.x, a.y, a.z, a.w, c.x, c.y, c.z, c.w};
  float s = 0.f, q = 0.f;
#pragma unroll
  for (int j = 0; j < 8; j++) { s += vals[j]; q += vals[j] * vals[j]; }
#pragma unroll
  for (int off = 1; off < 64; off <<= 1) {
    s += __shfl_xor(s, off);
    q += __shfl_xor(q, off);
  }
  float mean = s * (1.f / Dq);
  float var = q * (1.f / Dq) - mean * mean;
  float rstd = rsqrtf(var + 1e-5f);
  float of[8];
#pragma unroll
  for (int j = 0; j < 8; j++) {
    int col = lane * 8 + j;
    of[j] = (vals[j] - mean) * rstd * gamma[col] + beta[col];
  }
  float4* op = (float4*)(outf + (size_t)row * Dq + lane * 8);
  op[0] = make_float4(of[0], of[1], of[2], of[3]);
  op[1] = make_float4(of[4], of[5], of[6], of[7]);
  if (WB) {
    union { bf16 h[8]; ushort4 u[2]; } rr;
#pragma unroll
    for (int j = 0; j < 8; j++) rr.h[j] = (bf16)of[j];
    ushort4* ob = (ushort4*)(outb + (size_t)row * Dq + lane * 8);
    ob[0] = rr.u[0];
    ob[1] = rr.u[1];
  }
}

extern "C" void kernel_launch(void* const* d_in, const int* in_sizes, int n_in,
                              void* d_out, int out_size, void* d_ws, size_t ws_size,
                              hipStream_t stream) {
  const float* x      = (const float*)d_in[0];
  const float* w_qkv  = (const float*)d_in[1];
  const float* b_qkv  = (const float*)d_in[2];
  const float* w_proj = (const float*)d_in[3];
  const float* b_proj = (const float*)d_in[4];
  const float* ln1_g  = (const float*)d_in[5];
  const float* ln1_b  = (const float*)d_in[6];
  const float* w1     = (const float*)d_in[7];
  const float* b1     = (const float*)d_in[8];
  const float* w2     = (const float*)d_in[9];
  const float* b2     = (const float*)d_in[10];
  const float* ln2_g  = (const float*)d_in[11];
  const float* ln2_b  = (const float*)d_in[12];
  float* out = (float*)d_out;

  const int M = Bq * Nq;  // 8192 rows

  char* p = (char*)d_ws;
  auto alloc = [&](size_t bytes) -> void* {
    char* r = p;
    p += (bytes + 255) & ~(size_t)255;
    return (void*)r;
  };
  bf16* xb     = (bf16*)alloc((size_t)M * Dq * 2);        // x in bf16; later reused as att
  bf16* qkvb   = (bf16*)alloc((size_t)M * 3 * Dq * 2);
  bf16* wqkvT  = (bf16*)alloc((size_t)3 * Dq * Dq * 2);
  bf16* wprojT = (bf16*)alloc((size_t)Dq * Dq * 2);
  bf16* w1T    = (bf16*)alloc((size_t)Hq * Dq * 2);
  bf16* w2T    = (bf16*)alloc((size_t)Dq * Hq * 2);
  float* y1    = (float*)alloc((size_t)M * Dq * 4);       // also y2
  float* x1f   = (float*)alloc((size_t)M * Dq * 4);
  bf16* x1b    = (bf16*)alloc((size_t)M * Dq * 2);
  bf16* hb     = (bf16*)alloc((size_t)M * Hq * 2);
  bf16* attb   = xb;  // alias: xb consumed by qkv GEMM before attention writes

  dim3 tb(32, 8);
  k_cvt_bf16<<<(M * Dq / 4 + 255) / 256, 256, 0, stream>>>(x, xb, M * Dq);
  k_transpose_cvt<<<dim3((3 * Dq) / 32, Dq / 32), tb, 0, stream>>>(w_qkv, wqkvT, Dq, 3 * Dq);
  k_transpose_cvt<<<dim3(Dq / 32, Dq / 32), tb, 0, stream>>>(w_proj, wprojT, Dq, Dq);
  k_transpose_cvt<<<dim3(Hq / 32, Dq / 32), tb, 0, stream>>>(w1, w1T, Dq, Hq);
  k_transpose_cvt<<<dim3(Dq / 32, Hq / 32), tb, 0, stream>>>(w2, w2T, Hq, Dq);

  // qkv = x @ w_qkv + b_qkv   (bf16 out, row-major [M][1536])
  k_gemm<false, false, true><<<dim3((3 * Dq) / 128, M / 128), 256, 0, stream>>>(
      xb, wqkvT, b_qkv, nullptr, qkvb, M, 3 * Dq, Dq);
  // attention
  k_attn<<<dim3(Nq / 128, Bq * HEADS), 256, 0, stream>>>(qkvb, attb);
  // y1 = att @ w_proj + b_proj + x   (fp32 out)
  k_gemm<false, true, false><<<dim3(Dq / 128, M / 128), 256, 0, stream>>>(
      attb, wprojT, b_proj, x, y1, M, Dq, Dq);
  // x1 = LN1(y1) -> fp32 + bf16
  k_ln<true><<<M, 64, 0, stream>>>(y1, ln1_g, ln1_b, x1f, x1b);
  // h = gelu(x1 @ w1 + b1)  (bf16 out)
  k_gemm<true, false, true><<<dim3(Hq / 128, M / 128), 256, 0, stream>>>(
      x1b, w1T, b1, nullptr, hb, M, Hq, Dq);
  // y2 = h @ w2 + b2 + x1   (fp32 out, reuse y1 buffer)
  k_gemm<false, true, false><<<dim3(Dq / 128, M / 128), 256, 0, stream>>>(
      hb, w2T, b2, x1f, y1, M, Dq, Hq);
  // out = LN2(y2)
  k_ln<false><<<M, 64, 0, stream>>>(y1, ln2_g, ln2_b, out, nullptr);
}

// Round 3
// 268.053 us; speedup vs baseline: 1.2386x; 1.2386x over previous
//
#include <hip/hip_runtime.h>

#define HEADS 8
#define Bq 4
#define Nq 2048
#define Dq 512
#define Hq 2048

typedef __bf16 bf16;
typedef __bf16 bf16x8 __attribute__((ext_vector_type(8)));
typedef float f32x4 __attribute__((ext_vector_type(4)));

// ---------------- fp32 -> bf16 elementwise convert ----------------
__global__ __launch_bounds__(256) void k_cvt_bf16(const float* __restrict__ in,
                                                  bf16* __restrict__ out, int n) {
  int i = (blockIdx.x * 256 + threadIdx.x) * 4;
  if (i >= n) return;
  float4 v = *(const float4*)(in + i);
  union { bf16 h[4]; ushort4 u; } r;
  r.h[0] = (bf16)v.x; r.h[1] = (bf16)v.y; r.h[2] = (bf16)v.z; r.h[3] = (bf16)v.w;
  *(ushort4*)(out + i) = r.u;
}

// ---------------- transpose + convert: in fp32 [K][N] -> out bf16 [N][K] ----------------
__global__ __launch_bounds__(256) void k_transpose_cvt(const float* __restrict__ in,
                                                       bf16* __restrict__ out,
                                                       int K, int N) {
  __shared__ float t[32][33];
  const int n0 = blockIdx.x * 32, k0 = blockIdx.y * 32;
  const int tx = threadIdx.x, ty = threadIdx.y;
#pragma unroll
  for (int j = 0; j < 32; j += 8)
    t[ty + j][tx] = in[(size_t)(k0 + ty + j) * N + n0 + tx];
  __syncthreads();
#pragma unroll
  for (int j = 0; j < 32; j += 8)
    out[(size_t)(n0 + ty + j) * K + k0 + tx] = (bf16)t[tx][ty + j];
}

// ---------------- GEMM: C[M][N] = A[M][K](bf16) * BT[N][K]^T(bf16) + bias ----------------
// 128x128 tile, BK=32, 256 threads = 4 waves in 2x2. mfma_f32_16x16x32_bf16.
// VTOUT: blocks with n0>=1024 (V part of qkv) store TRANSPOSED into vt[B*H][64][Nq].
template <bool GELU, bool RESID, bool STORE_BF16, bool VTOUT>
__global__ __launch_bounds__(256) void k_gemm(const bf16* __restrict__ A,
                                              const bf16* __restrict__ BT,
                                              const float* __restrict__ bias,
                                              const float* __restrict__ resid,
                                              void* __restrict__ Cout,
                                              bf16* __restrict__ vt,
                                              int M, int N, int K) {
  __shared__ bf16 As[128 * 40];  // +8 pad
  __shared__ bf16 Bs[128 * 40];
  const int m0 = blockIdx.y * 128, n0 = blockIdx.x * 128;
  const int tid = threadIdx.x, lane = tid & 63, wid = tid >> 6;
  const int wr = wid >> 1, wc = wid & 1;
  const int r16 = lane & 15, g = lane >> 4;

  f32x4 acc[4][4] = {};

  for (int k0 = 0; k0 < K; k0 += 32) {
    __syncthreads();
#pragma unroll
    for (int i = 0; i < 2; i++) {
      int c = tid + i * 256;
      int row = c >> 2, kc = c & 3;
      *(int4*)(As + row * 40 + kc * 8) =
          *(const int4*)(A + (size_t)(m0 + row) * K + k0 + kc * 8);
      *(int4*)(Bs + row * 40 + kc * 8) =
          *(const int4*)(BT + (size_t)(n0 + row) * K + k0 + kc * 8);
    }
    __syncthreads();

    bf16x8 af[4], bfr[4];
#pragma unroll
    for (int mi = 0; mi < 4; mi++)
      af[mi] = *(const bf16x8*)(As + (wr * 64 + mi * 16 + r16) * 40 + g * 8);
#pragma unroll
    for (int ni = 0; ni < 4; ni++)
      bfr[ni] = *(const bf16x8*)(Bs + (wc * 64 + ni * 16 + r16) * 40 + g * 8);
#pragma unroll
    for (int mi = 0; mi < 4; mi++)
#pragma unroll
      for (int ni = 0; ni < 4; ni++)
        acc[mi][ni] = __builtin_amdgcn_mfma_f32_16x16x32_bf16(af[mi], bfr[ni],
                                                              acc[mi][ni], 0, 0, 0);
  }

  if (VTOUT && n0 >= 1024) {
    // V block of qkv: store transposed to vt[(b*HEADS+h)*64+e][n]
#pragma unroll
    for (int mi = 0; mi < 4; mi++)
#pragma unroll
      for (int ni = 0; ni < 4; ni++) {
        int col = n0 + wc * 64 + ni * 16 + r16;
        int vd = col - 1024;
        int hh = vd >> 6, e = vd & 63;
        float bv = bias[col];
        int row0 = m0 + wr * 64 + mi * 16 + 4 * g;
        int bb = row0 >> 11, n = row0 & 2047;
        union { bf16 h[4]; ushort4 u; } r4;
#pragma unroll
        for (int r = 0; r < 4; r++) r4.h[r] = (bf16)(acc[mi][ni][r] + bv);
        *(ushort4*)(vt + ((size_t)(bb * HEADS + hh) * 64 + e) * Nq + n) = r4.u;
      }
    return;
  }

#pragma unroll
  for (int mi = 0; mi < 4; mi++)
#pragma unroll
    for (int ni = 0; ni < 4; ni++) {
      int col = n0 + wc * 64 + ni * 16 + r16;
      float bv = bias[col];
#pragma unroll
      for (int r = 0; r < 4; r++) {
        int row = m0 + wr * 64 + mi * 16 + 4 * g + r;
        float v = acc[mi][ni][r] + bv;
        if (GELU) v = 0.5f * v * (1.f + erff(v * 0.70710678118654752f));
        if (RESID) v += resid[(size_t)row * N + col];
        if (STORE_BF16) ((bf16*)Cout)[(size_t)row * N + col] = (bf16)v;
        else            ((float*)Cout)[(size_t)row * N + col] = v;
      }
    }
}

// ---------------- flash attention, swapped-QK^T structure ----------------
// qkv bf16 [B*N][1536] (Q,K cols 0..1023), vt bf16 [B*H][64][Nq] (pre-transposed V).
// grid (Nq/128, B*HEADS), 256 thr = 4 waves, 32 q-rows/wave, KVBLK=64.
// S^T = mfma(A=K, B=Q): lane holds P^T[kv=4g+reg][q=r16] -> softmax = 15 fmax + 2 shfl.
// PV A-frag redistribution: dest (r16, g=2gh+gl) word w needs
//   P^T[32kk + 16gh + 8gl + 2w .. +1][r16], held by src lane g'=2gl+(w>>1) in
//   tile nt=2kk+gh, pair p=w&1. nt depends on DEST gh -> need 2 shuffles
//   (one per nt, selector compile-time) + dest-side select by (g&2).
__global__ __launch_bounds__(256) void k_attn(const bf16* __restrict__ qkv,
                                              const bf16* __restrict__ vt,
                                              bf16* __restrict__ att) {
  __shared__ bf16 Ks[64 * 72];  // K-tile [kv][e], pad 72
  __shared__ bf16 Vs[64 * 72];  // V^T-tile [e][kv], pad 72
  const int qt = blockIdx.x, b = blockIdx.y >> 3, h = blockIdx.y & 7;
  const int tid = threadIdx.x, lane = tid & 63, wid = tid >> 6;
  const int r16 = lane & 15, g = lane >> 4;
  const size_t base = (size_t)b * Nq * (3 * Dq);
  const bf16* qp = qkv + base + h * 64;
  const bf16* kp = qkv + base + Dq + h * 64;
  const bf16* vtp = vt + (size_t)(b * HEADS + h) * 64 * Nq;
  const int q0 = qt * 128 + wid * 32;

  // Q as B-operand: qf[mi][kk] holds Q[q=q0+mi*16+r16][e=kk*32+8g+i]
  bf16x8 qf[2][2];
#pragma unroll
  for (int mi = 0; mi < 2; mi++)
#pragma unroll
    for (int kk = 0; kk < 2; kk++)
      qf[mi][kk] = *(const bf16x8*)(qp + (size_t)(q0 + mi * 16 + r16) * (3 * Dq) +
                                    kk * 32 + g * 8);

  f32x4 o[2][4] = {};
  float mrun[2] = {-INFINITY, -INFINITY}, lrun[2] = {0.f, 0.f};

  for (int kv0 = 0; kv0 < Nq; kv0 += 64) {
    __syncthreads();
#pragma unroll
    for (int it = 0; it < 2; it++) {
      int t = tid + it * 256;          // 0..511: 64 rows x 8 chunks of 16B
      int row = t >> 3, ch = t & 7;
      *(int4*)(Ks + row * 72 + ch * 8) =
          *(const int4*)(kp + (size_t)(kv0 + row) * (3 * Dq) + ch * 8);
      *(int4*)(Vs + row * 72 + ch * 8) =
          *(const int4*)(vtp + (size_t)row * Nq + kv0 + ch * 8);
    }
    __syncthreads();

    // S^T[kv][q] tiles: s[nt][mi], nt = kv 16-tile
    f32x4 s[4][2] = {};
#pragma unroll
    for (int kk = 0; kk < 2; kk++)
#pragma unroll
      for (int nt = 0; nt < 4; nt++) {
        bf16x8 kf = *(const bf16x8*)(Ks + (nt * 16 + r16) * 72 + kk * 32 + g * 8);
#pragma unroll
        for (int mi = 0; mi < 2; mi++)
          s[nt][mi] = __builtin_amdgcn_mfma_f32_16x16x32_bf16(kf, qf[mi][kk],
                                                              s[nt][mi], 0, 0, 0);
      }

    // online softmax: lane owns 16 kv values per q-column r16
    float scale[2];
    bool changed = false;
#pragma unroll
    for (int mi = 0; mi < 2; mi++) {
      float mx = s[0][mi][0];
#pragma unroll
      for (int nt = 0; nt < 4; nt++)
#pragma unroll
        for (int r = 0; r < 4; r++) mx = fmaxf(mx, s[nt][mi][r]);
      mx = fmaxf(mx, __shfl_xor(mx, 16));
      mx = fmaxf(mx, __shfl_xor(mx, 32));
      float mold = mrun[mi];
      float mn = fmaxf(mold, mx);
      changed |= (mn > mold);
      scale[mi] = __expf(mold - mn);
      mrun[mi] = mn;
      float rs = 0.f;
#pragma unroll
      for (int nt = 0; nt < 4; nt++)
#pragma unroll
        for (int r = 0; r < 4; r++) {
          float pv = __expf(s[nt][mi][r] - mn);
          s[nt][mi][r] = pv;
          rs += pv;
        }
      rs += __shfl_xor(rs, 16);
      rs += __shfl_xor(rs, 32);
      lrun[mi] = lrun[mi] * scale[mi] + rs;
    }

    // deferred O-rescale: only when a new max appeared anywhere in the wave
    if (__any(changed)) {
#pragma unroll
      for (int mi = 0; mi < 2; mi++) {
        float so[4];
#pragma unroll
        for (int r = 0; r < 4; r++) so[r] = __shfl(scale[mi], 4 * g + r);
#pragma unroll
        for (int ot = 0; ot < 4; ot++)
#pragma unroll
          for (int r = 0; r < 4; r++) o[mi][ot][r] *= so[r];
      }
    }

    // pack P^T to bf16 pairs: packed[nt][mi][p] = (reg 2p, 2p+1)
    unsigned packed[4][2][2];
#pragma unroll
    for (int nt = 0; nt < 4; nt++)
#pragma unroll
      for (int mi = 0; mi < 2; mi++)
#pragma unroll
        for (int p = 0; p < 2; p++) {
          union { bf16 h[2]; unsigned u; } pk;
          pk.h[0] = (bf16)s[nt][mi][2 * p];
          pk.h[1] = (bf16)s[nt][mi][2 * p + 1];
          packed[nt][mi][p] = pk.u;
        }

    // PV: redistribute P to A-frags (row=q=r16, k=kv), B=V^T from LDS
#pragma unroll
    for (int kk = 0; kk < 2; kk++) {
      bf16x8 vf[4];
#pragma unroll
      for (int ot = 0; ot < 4; ot++)
        vf[ot] = *(const bf16x8*)(Vs + (ot * 16 + r16) * 72 + kk * 32 + g * 8);
#pragma unroll
      for (int mi = 0; mi < 2; mi++) {
        union { unsigned w[4]; bf16x8 v; } pa;
#pragma unroll
        for (int w = 0; w < 4; w++) {
          int srcLane = ((2 * (g & 1) + (w >> 1)) << 4) | r16;
          unsigned lo = __shfl((int)packed[2 * kk][mi][w & 1], srcLane);
          unsigned hi = __shfl((int)packed[2 * kk + 1][mi][w & 1], srcLane);
          pa.w[w] = (g & 2) ? hi : lo;
        }
#pragma unroll
        for (int ot = 0; ot < 4; ot++)
          o[mi][ot] = __builtin_amdgcn_mfma_f32_16x16x32_bf16(pa.v, vf[ot],
                                                              o[mi][ot], 0, 0, 0);
      }
    }
  }

  // epilogue: O row=q=4g+r, col=e=r16; l lives on lane r16=q -> shfl
#pragma unroll
  for (int mi = 0; mi < 2; mi++) {
    float li[4];
#pragma unroll
    for (int r = 0; r < 4; r++) li[r] = 0.125f / __shfl(lrun[mi], 4 * g + r);
#pragma unroll
    for (int ot = 0; ot < 4; ot++)
#pragma unroll
      for (int r = 0; r < 4; r++) {
        int row = q0 + mi * 16 + 4 * g + r;
        int col = h * 64 + ot * 16 + r16;
        att[((size_t)b * Nq + row) * Dq + col] = (bf16)(o[mi][ot][r] * li[r]);
      }
  }
}

// ---------------- LayerNorm over D=512, one wave per row ----------------
template <bool WB>
__global__ __launch_bounds__(64) void k_ln(const float* __restrict__ in,
                                           const float* __restrict__ gamma,
                                           const float* __restrict__ beta,
                                           float* __restrict__ outf,
                                           bf16* __restrict__ outb) {
  const int row = blockIdx.x, lane = threadIdx.x;
  const float* p = in + (size_t)row * Dq + lane * 8;
  float4 a = *(const float4*)p;
  float4 c = *(const float4*)(p + 4);
  float vals[8] = {a.x, a.y, a.z, a.w, c.x, c.y, c.z, c.w};
  float s = 0.f, q = 0.f;
#pragma unroll
  for (int j = 0; j < 8; j++) { s += vals[j]; q += vals[j] * vals[j]; }
#pragma unroll
  for (int off = 1; off < 64; off <<= 1) {
    s += __shfl_xor(s, off);
    q += __shfl_xor(q, off);
  }
  float mean = s * (1.f / Dq);
  float var = q * (1.f / Dq) - mean * mean;
  float rstd = rsqrtf(var + 1e-5f);
  float of[8];
#pragma unroll
  for (int j = 0; j < 8; j++) {
    int col = lane * 8 + j;
    of[j] = (vals[j] - mean) * rstd * gamma[col] + beta[col];
  }
  float4* op = (float4*)(outf + (size_t)row * Dq + lane * 8);
  op[0] = make_float4(of[0], of[1], of[2], of[3]);
  op[1] = make_float4(of[4], of[5], of[6], of[7]);
  if (WB) {
    union { bf16 h[8]; ushort4 u[2]; } rr;
#pragma unroll
    for (int j = 0; j < 8; j++) rr.h[j] = (bf16)of[j];
    ushort4* ob = (ushort4*)(outb + (size_t)row * Dq + lane * 8);
    ob[0] = rr.u[0];
    ob[1] = rr.u[1];
  }
}

extern "C" void kernel_launch(void* const* d_in, const int* in_sizes, int n_in,
                              void* d_out, int out_size, void* d_ws, size_t ws_size,
                              hipStream_t stream) {
  const float* x      = (const float*)d_in[0];
  const float* w_qkv  = (const float*)d_in[1];
  const float* b_qkv  = (const float*)d_in[2];
  const float* w_proj = (const float*)d_in[3];
  const float* b_proj = (const float*)d_in[4];
  const float* ln1_g  = (const float*)d_in[5];
  const float* ln1_b  = (const float*)d_in[6];
  const float* w1     = (const float*)d_in[7];
  const float* b1     = (const float*)d_in[8];
  const float* w2     = (const float*)d_in[9];
  const float* b2     = (const float*)d_in[10];
  const float* ln2_g  = (const float*)d_in[11];
  const float* ln2_b  = (const float*)d_in[12];
  float* out = (float*)d_out;

  const int M = Bq * Nq;  // 8192 rows

  char* p = (char*)d_ws;
  auto alloc = [&](size_t bytes) -> void* {
    char* r = p;
    p += (bytes + 255) & ~(size_t)255;
    return (void*)r;
  };
  bf16* xb     = (bf16*)alloc((size_t)M * Dq * 2);        // x bf16; later reused as att
  bf16* qkvb   = (bf16*)alloc((size_t)M * 3 * Dq * 2);
  bf16* wqkvT  = (bf16*)alloc((size_t)3 * Dq * Dq * 2);
  bf16* wprojT = (bf16*)alloc((size_t)Dq * Dq * 2);
  bf16* w1T    = (bf16*)alloc((size_t)Hq * Dq * 2);
  bf16* w2T    = (bf16*)alloc((size_t)Dq * Hq * 2);
  float* y1    = (float*)alloc((size_t)M * Dq * 4);       // also y2
  float* x1f   = (float*)alloc((size_t)M * Dq * 4);
  bf16* x1b    = (bf16*)alloc((size_t)M * Dq * 2);
  bf16* hb     = (bf16*)alloc((size_t)M * Hq * 2);
  bf16* attb   = xb;   // alias: xb consumed by qkv GEMM before attention writes
  bf16* vtb    = hb;   // alias: hb written by ffn1 only after attention is done

  dim3 tb(32, 8);
  k_cvt_bf16<<<(M * Dq / 4 + 255) / 256, 256, 0, stream>>>(x, xb, M * Dq);
  k_transpose_cvt<<<dim3((3 * Dq) / 32, Dq / 32), tb, 0, stream>>>(w_qkv, wqkvT, Dq, 3 * Dq);
  k_transpose_cvt<<<dim3(Dq / 32, Dq / 32), tb, 0, stream>>>(w_proj, wprojT, Dq, Dq);
  k_transpose_cvt<<<dim3(Hq / 32, Dq / 32), tb, 0, stream>>>(w1, w1T, Dq, Hq);
  k_transpose_cvt<<<dim3(Dq / 32, Hq / 32), tb, 0, stream>>>(w2, w2T, Hq, Dq);

  // qkv = x @ w_qkv + b_qkv  (Q,K -> qkvb natural; V -> vtb transposed)
  k_gemm<false, false, true, true><<<dim3((3 * Dq) / 128, M / 128), 256, 0, stream>>>(
      xb, wqkvT, b_qkv, nullptr, qkvb, vtb, M, 3 * Dq, Dq);
  // attention
  k_attn<<<dim3(Nq / 128, Bq * HEADS), 256, 0, stream>>>(qkvb, vtb, attb);
  // y1 = att @ w_proj + b_proj + x
  k_gemm<false, true, false, false><<<dim3(Dq / 128, M / 128), 256, 0, stream>>>(
      attb, wprojT, b_proj, x, y1, nullptr, M, Dq, Dq);
  // x1 = LN1(y1) -> fp32 + bf16
  k_ln<true><<<M, 64, 0, stream>>>(y1, ln1_g, ln1_b, x1f, x1b);
  // h = gelu(x1 @ w1 + b1)
  k_gemm<true, false, true, false><<<dim3(Hq / 128, M / 128), 256, 0, stream>>>(
      x1b, w1T, b1, nullptr, hb, nullptr, M, Hq, Dq);
  // y2 = h @ w2 + b2 + x1
  k_gemm<false, true, false, false><<<dim3(Dq / 128, M / 128), 256, 0, stream>>>(
      hb, w2T, b2, x1f, y1, nullptr, M, Dq, Hq);
  // out = LN2(y2)
  k_ln<false><<<M, 64, 0, stream>>>(y1, ln2_g, ln2_b, out, nullptr);
}

// Round 4
// 240.095 us; speedup vs baseline: 1.3828x; 1.1164x over previous
//
#include <hip/hip_runtime.h>

#define HEADS 8
#define Bq 4
#define Nq 2048
#define Dq 512
#define Hq 2048

typedef __bf16 bf16;
typedef __bf16 bf16x8 __attribute__((ext_vector_type(8)));
typedef float f32x4 __attribute__((ext_vector_type(4)));

__device__ __forceinline__ void gload16(const bf16* g, bf16* s) {
  __builtin_amdgcn_global_load_lds(
      (const __attribute__((address_space(1))) void*)g,
      (__attribute__((address_space(3))) void*)s, 16, 0, 0);
}

// ---------------- fp32 -> bf16 elementwise convert ----------------
__global__ __launch_bounds__(256) void k_cvt_bf16(const float* __restrict__ in,
                                                  bf16* __restrict__ out, int n) {
  int i = (blockIdx.x * 256 + threadIdx.x) * 4;
  if (i >= n) return;
  float4 v = *(const float4*)(in + i);
  union { bf16 h[4]; ushort4 u; } r;
  r.h[0] = (bf16)v.x; r.h[1] = (bf16)v.y; r.h[2] = (bf16)v.z; r.h[3] = (bf16)v.w;
  *(ushort4*)(out + i) = r.u;
}

// ---------------- transpose + convert: in fp32 [K][N] -> out bf16 [N][K] ----------------
__global__ __launch_bounds__(256) void k_transpose_cvt(const float* __restrict__ in,
                                                       bf16* __restrict__ out,
                                                       int K, int N) {
  __shared__ float t[32][33];
  const int n0 = blockIdx.x * 32, k0 = blockIdx.y * 32;
  const int tx = threadIdx.x, ty = threadIdx.y;
#pragma unroll
  for (int j = 0; j < 32; j += 8)
    t[ty + j][tx] = in[(size_t)(k0 + ty + j) * N + n0 + tx];
  __syncthreads();
#pragma unroll
  for (int j = 0; j < 32; j += 8)
    out[(size_t)(n0 + ty + j) * K + k0 + tx] = (bf16)t[tx][ty + j];
}

// ---------------- GEMM: C[M][N] = A[M][K](bf16) * BT[N][K]^T + bias ----------------
// 128x128 tile, BK=64, 256 thr = 4 waves (2x2). global_load_lds width-16 staging,
// double-buffered 2-phase (stage t+1 -> compute t -> one barrier per K-step).
// LDS swizzle per rule #21: linear dest + inverse-XOR global source
// (chunk c = (l&7)^(l>>3)) + XOR on ds_read ((4kk+g)^(row&7)) -> conflict-free b128.
// VTOUT: blocks with n0>=1024 (V of qkv) store TRANSPOSED into vt[B*H][64][Nq].
template <bool GELU, bool RESID, bool STORE_BF16, bool VTOUT>
__global__ __launch_bounds__(256) void k_gemm(const bf16* __restrict__ A,
                                              const bf16* __restrict__ BT,
                                              const float* __restrict__ bias,
                                              const float* __restrict__ resid,
                                              void* __restrict__ Cout,
                                              bf16* __restrict__ vt,
                                              int M, int N, int K) {
  __shared__ bf16 As[2][128 * 64];
  __shared__ bf16 Bs[2][128 * 64];
  const int m0 = blockIdx.y * 128, n0 = blockIdx.x * 128;
  const int tid = threadIdx.x, lane = tid & 63, wid = tid >> 6;
  const int wr = wid >> 1, wc = wid & 1;
  const int r16 = lane & 15, g = lane >> 4;

  // per-lane staging geometry (wave covers 32 rows: 4 instrs x 8 rows)
  const int srow = (lane >> 3);            // 0..7 within instr
  const int schunk = (lane & 7) ^ srow;    // inverse-swizzled source chunk

  f32x4 acc[4][4] = {};

  const int NT = K >> 6;
  // prologue: stage tile 0 into buf 0
#pragma unroll
  for (int i = 0; i < 4; i++) {
    int rl = wid * 32 + i * 8 + srow;
    gload16(A + (size_t)(m0 + rl) * K + schunk * 8, &As[0][(wid * 32 + i * 8) * 64]);
    gload16(BT + (size_t)(n0 + rl) * K + schunk * 8, &Bs[0][(wid * 32 + i * 8) * 64]);
  }
  __syncthreads();

  for (int t = 0; t < NT; t++) {
    const int cur = t & 1;
    if (t + 1 < NT) {
      const int kt = (t + 1) << 6;
#pragma unroll
      for (int i = 0; i < 4; i++) {
        int rl = wid * 32 + i * 8 + srow;
        gload16(A + (size_t)(m0 + rl) * K + kt + schunk * 8,
                &As[cur ^ 1][(wid * 32 + i * 8) * 64]);
        gload16(BT + (size_t)(n0 + rl) * K + kt + schunk * 8,
                &Bs[cur ^ 1][(wid * 32 + i * 8) * 64]);
      }
    }
    const bf16* Ab = As[cur];
    const bf16* Bb = Bs[cur];
#pragma unroll
    for (int kk = 0; kk < 2; kk++) {
      bf16x8 af[4], bfr[4];
#pragma unroll
      for (int mi = 0; mi < 4; mi++) {
        int row = wr * 64 + mi * 16 + r16;
        af[mi] = *(const bf16x8*)(Ab + row * 64 + (((4 * kk + g) ^ (row & 7)) * 8));
      }
#pragma unroll
      for (int ni = 0; ni < 4; ni++) {
        int row = wc * 64 + ni * 16 + r16;
        bfr[ni] = *(const bf16x8*)(Bb + row * 64 + (((4 * kk + g) ^ (row & 7)) * 8));
      }
#pragma unroll
      for (int mi = 0; mi < 4; mi++)
#pragma unroll
        for (int ni = 0; ni < 4; ni++)
          acc[mi][ni] = __builtin_amdgcn_mfma_f32_16x16x32_bf16(af[mi], bfr[ni],
                                                                acc[mi][ni], 0, 0, 0);
    }
    __syncthreads();  // drains stage(t+1), protects buf reuse
  }

  if (VTOUT && n0 >= 1024) {
#pragma unroll
    for (int mi = 0; mi < 4; mi++)
#pragma unroll
      for (int ni = 0; ni < 4; ni++) {
        int col = n0 + wc * 64 + ni * 16 + r16;
        int vd = col - 1024;
        int hh = vd >> 6, e = vd & 63;
        float bv = bias[col];
        int row0 = m0 + wr * 64 + mi * 16 + 4 * g;
        int bb = row0 >> 11, n = row0 & 2047;
        union { bf16 h[4]; ushort4 u; } r4;
#pragma unroll
        for (int r = 0; r < 4; r++) r4.h[r] = (bf16)(acc[mi][ni][r] + bv);
        *(ushort4*)(vt + ((size_t)(bb * HEADS + hh) * 64 + e) * Nq + n) = r4.u;
      }
    return;
  }

#pragma unroll
  for (int mi = 0; mi < 4; mi++)
#pragma unroll
    for (int ni = 0; ni < 4; ni++) {
      int col = n0 + wc * 64 + ni * 16 + r16;
      float bv = bias[col];
#pragma unroll
      for (int r = 0; r < 4; r++) {
        int row = m0 + wr * 64 + mi * 16 + 4 * g + r;
        float v = acc[mi][ni][r] + bv;
        if (GELU) v = 0.5f * v * (1.f + erff(v * 0.70710678118654752f));
        if (RESID) v += resid[(size_t)row * N + col];
        if (STORE_BF16) ((bf16*)Cout)[(size_t)row * N + col] = (bf16)v;
        else            ((float*)Cout)[(size_t)row * N + col] = v;
      }
    }
}

// ---------------- flash attention, swapped-QK^T, 16 q-rows/wave ----------------
// grid (Nq/64, B*HEADS), 256 thr = 4 waves, 16 q-rows/wave, KVBLK=64.
// S^T = mfma(A=K, B=Q): lane holds P^T[kv=4g+reg][q=r16].
// T13 defer-max (THR=8): skip rescale while tile max stays within 8 of running max.
__global__ __launch_bounds__(256) void k_attn(const bf16* __restrict__ qkv,
                                              const bf16* __restrict__ vt,
                                              bf16* __restrict__ att) {
  __shared__ bf16 Ks[64 * 72];  // K-tile [kv][e], pad 72
  __shared__ bf16 Vs[64 * 72];  // V^T-tile [e][kv], pad 72
  const int qt = blockIdx.x, b = blockIdx.y >> 3, h = blockIdx.y & 7;
  const int tid = threadIdx.x, lane = tid & 63, wid = tid >> 6;
  const int r16 = lane & 15, g = lane >> 4;
  const size_t base = (size_t)b * Nq * (3 * Dq);
  const bf16* qp = qkv + base + h * 64;
  const bf16* kp = qkv + base + Dq + h * 64;
  const bf16* vtp = vt + (size_t)(b * HEADS + h) * 64 * Nq;
  const int q0 = qt * 64 + wid * 16;

  bf16x8 qf[2];
#pragma unroll
  for (int kk = 0; kk < 2; kk++)
    qf[kk] = *(const bf16x8*)(qp + (size_t)(q0 + r16) * (3 * Dq) + kk * 32 + g * 8);

  f32x4 o[4] = {};
  float mrun = -INFINITY, lrun = 0.f;

  for (int kv0 = 0; kv0 < Nq; kv0 += 64) {
    __syncthreads();
#pragma unroll
    for (int it = 0; it < 2; it++) {
      int t = tid + it * 256;
      int row = t >> 3, ch = t & 7;
      *(int4*)(Ks + row * 72 + ch * 8) =
          *(const int4*)(kp + (size_t)(kv0 + row) * (3 * Dq) + ch * 8);
      *(int4*)(Vs + row * 72 + ch * 8) =
          *(const int4*)(vtp + (size_t)row * Nq + kv0 + ch * 8);
    }
    __syncthreads();

    // S^T[kv][q]: s[nt], nt = kv 16-tile
    f32x4 s[4] = {};
#pragma unroll
    for (int kk = 0; kk < 2; kk++)
#pragma unroll
      for (int nt = 0; nt < 4; nt++) {
        bf16x8 kf = *(const bf16x8*)(Ks + (nt * 16 + r16) * 72 + kk * 32 + g * 8);
        s[nt] = __builtin_amdgcn_mfma_f32_16x16x32_bf16(kf, qf[kk], s[nt], 0, 0, 0);
      }

    // online softmax with defer-max threshold
    float mx = s[0][0];
#pragma unroll
    for (int nt = 0; nt < 4; nt++)
#pragma unroll
      for (int r = 0; r < 4; r++) mx = fmaxf(mx, s[nt][r]);
    mx = fmaxf(mx, __shfl_xor(mx, 16));
    mx = fmaxf(mx, __shfl_xor(mx, 32));
    const float mold = mrun;
    const bool need = (mx > mold + 8.f);
    const float mn = need ? mx : mold;
    mrun = mn;
    float rs = 0.f;
#pragma unroll
    for (int nt = 0; nt < 4; nt++)
#pragma unroll
      for (int r = 0; r < 4; r++) {
        float pv = __expf(s[nt][r] - mn);
        s[nt][r] = pv;
        rs += pv;
      }
    rs += __shfl_xor(rs, 16);
    rs += __shfl_xor(rs, 32);
    const float scale = need ? __expf(mold - mn) : 1.f;
    lrun = need ? lrun * scale + rs : lrun + rs;

    if (__any(need)) {
      float so[4];
#pragma unroll
      for (int r = 0; r < 4; r++) so[r] = __shfl(scale, 4 * g + r);
#pragma unroll
      for (int ot = 0; ot < 4; ot++)
#pragma unroll
        for (int r = 0; r < 4; r++) o[ot][r] *= so[r];
    }

    // pack P^T to bf16 pairs: packed[nt][p] = (reg 2p, 2p+1)
    unsigned packed[4][2];
#pragma unroll
    for (int nt = 0; nt < 4; nt++)
#pragma unroll
      for (int p = 0; p < 2; p++) {
        union { bf16 h[2]; unsigned u; } pk;
        pk.h[0] = (bf16)s[nt][2 * p];
        pk.h[1] = (bf16)s[nt][2 * p + 1];
        packed[nt][p] = pk.u;
      }

    // PV: dest (r16, g=2gh+gl) word w needs P^T[32kk+16gh+8gl+2w][r16]
    // from src lane g'=2gl+(w>>1), tile nt=2kk+gh -> 2 shuffles + dest select.
#pragma unroll
    for (int kk = 0; kk < 2; kk++) {
      union { unsigned w[4]; bf16x8 v; } pa;
#pragma unroll
      for (int w = 0; w < 4; w++) {
        int srcLane = ((2 * (g & 1) + (w >> 1)) << 4) | r16;
        unsigned lo = __shfl((int)packed[2 * kk][w & 1], srcLane);
        unsigned hi = __shfl((int)packed[2 * kk + 1][w & 1], srcLane);
        pa.w[w] = (g & 2) ? hi : lo;
      }
#pragma unroll
      for (int ot = 0; ot < 4; ot++) {
        bf16x8 vf = *(const bf16x8*)(Vs + (ot * 16 + r16) * 72 + kk * 32 + g * 8);
        o[ot] = __builtin_amdgcn_mfma_f32_16x16x32_bf16(pa.v, vf, o[ot], 0, 0, 0);
      }
    }
  }

  // epilogue: O row=q=4g+r, col=e=r16; l lives on lane r16=q -> shfl
  float li[4];
#pragma unroll
  for (int r = 0; r < 4; r++) li[r] = 0.125f / __shfl(lrun, 4 * g + r);
#pragma unroll
  for (int ot = 0; ot < 4; ot++)
#pragma unroll
    for (int r = 0; r < 4; r++) {
      int row = q0 + 4 * g + r;
      int col = h * 64 + ot * 16 + r16;
      att[((size_t)b * Nq + row) * Dq + col] = (bf16)(o[ot][r] * li[r]);
    }
}

// ---------------- LayerNorm over D=512, one wave per row ----------------
template <bool WB>
__global__ __launch_bounds__(64) void k_ln(const float* __restrict__ in,
                                           const float* __restrict__ gamma,
                                           const float* __restrict__ beta,
                                           float* __restrict__ outf,
                                           bf16* __restrict__ outb) {
  const int row = blockIdx.x, lane = threadIdx.x;
  const float* p = in + (size_t)row * Dq + lane * 8;
  float4 a = *(const float4*)p;
  float4 c = *(const float4*)(p + 4);
  float vals[8] = {a.x, a.y, a.z, a.w, c.x, c.y, c.z, c.w};
  float s = 0.f, q = 0.f;
#pragma unroll
  for (int j = 0; j < 8; j++) { s += vals[j]; q += vals[j] * vals[j]; }
#pragma unroll
  for (int off = 1; off < 64; off <<= 1) {
    s += __shfl_xor(s, off);
    q += __shfl_xor(q, off);
  }
  float mean = s * (1.f / Dq);
  float var = q * (1.f / Dq) - mean * mean;
  float rstd = rsqrtf(var + 1e-5f);
  float of[8];
#pragma unroll
  for (int j = 0; j < 8; j++) {
    int col = lane * 8 + j;
    of[j] = (vals[j] - mean) * rstd * gamma[col] + beta[col];
  }
  float4* op = (float4*)(outf + (size_t)row * Dq + lane * 8);
  op[0] = make_float4(of[0], of[1], of[2], of[3]);
  op[1] = make_float4(of[4], of[5], of[6], of[7]);
  if (WB) {
    union { bf16 h[8]; ushort4 u[2]; } rr;
#pragma unroll
    for (int j = 0; j < 8; j++) rr.h[j] = (bf16)of[j];
    ushort4* ob = (ushort4*)(outb + (size_t)row * Dq + lane * 8);
    ob[0] = rr.u[0];
    ob[1] = rr.u[1];
  }
}

extern "C" void kernel_launch(void* const* d_in, const int* in_sizes, int n_in,
                              void* d_out, int out_size, void* d_ws, size_t ws_size,
                              hipStream_t stream) {
  const float* x      = (const float*)d_in[0];
  const float* w_qkv  = (const float*)d_in[1];
  const float* b_qkv  = (const float*)d_in[2];
  const float* w_proj = (const float*)d_in[3];
  const float* b_proj = (const float*)d_in[4];
  const float* ln1_g  = (const float*)d_in[5];
  const float* ln1_b  = (const float*)d_in[6];
  const float* w1     = (const float*)d_in[7];
  const float* b1     = (const float*)d_in[8];
  const float* w2     = (const float*)d_in[9];
  const float* b2     = (const float*)d_in[10];
  const float* ln2_g  = (const float*)d_in[11];
  const float* ln2_b  = (const float*)d_in[12];
  float* out = (float*)d_out;

  const int M = Bq * Nq;  // 8192 rows

  char* p = (char*)d_ws;
  auto alloc = [&](size_t bytes) -> void* {
    char* r = p;
    p += (bytes + 255) & ~(size_t)255;
    return (void*)r;
  };
  bf16* xb     = (bf16*)alloc((size_t)M * Dq * 2);        // x bf16; later reused as att
  bf16* qkvb   = (bf16*)alloc((size_t)M * 3 * Dq * 2);
  bf16* wqkvT  = (bf16*)alloc((size_t)3 * Dq * Dq * 2);
  bf16* wprojT = (bf16*)alloc((size_t)Dq * Dq * 2);
  bf16* w1T    = (bf16*)alloc((size_t)Hq * Dq * 2);
  bf16* w2T    = (bf16*)alloc((size_t)Dq * Hq * 2);
  float* y1    = (float*)alloc((size_t)M * Dq * 4);       // also y2
  float* x1f   = (float*)alloc((size_t)M * Dq * 4);
  bf16* x1b    = (bf16*)alloc((size_t)M * Dq * 2);
  bf16* hb     = (bf16*)alloc((size_t)M * Hq * 2);
  bf16* attb   = xb;   // alias: xb consumed by qkv GEMM before attention writes
  bf16* vtb    = hb;   // alias: hb written by ffn1 only after attention is done

  dim3 tb(32, 8);
  k_cvt_bf16<<<(M * Dq / 4 + 255) / 256, 256, 0, stream>>>(x, xb, M * Dq);
  k_transpose_cvt<<<dim3((3 * Dq) / 32, Dq / 32), tb, 0, stream>>>(w_qkv, wqkvT, Dq, 3 * Dq);
  k_transpose_cvt<<<dim3(Dq / 32, Dq / 32), tb, 0, stream>>>(w_proj, wprojT, Dq, Dq);
  k_transpose_cvt<<<dim3(Hq / 32, Dq / 32), tb, 0, stream>>>(w1, w1T, Dq, Hq);
  k_transpose_cvt<<<dim3(Dq / 32, Hq / 32), tb, 0, stream>>>(w2, w2T, Hq, Dq);

  // qkv = x @ w_qkv + b_qkv  (Q,K -> qkvb natural; V -> vtb transposed)
  k_gemm<false, false, true, true><<<dim3((3 * Dq) / 128, M / 128), 256, 0, stream>>>(
      xb, wqkvT, b_qkv, nullptr, qkvb, vtb, M, 3 * Dq, Dq);
  // attention
  k_attn<<<dim3(Nq / 64, Bq * HEADS), 256, 0, stream>>>(qkvb, vtb, attb);
  // y1 = att @ w_proj + b_proj + x
  k_gemm<false, true, false, false><<<dim3(Dq / 128, M / 128), 256, 0, stream>>>(
      attb, wprojT, b_proj, x, y1, nullptr, M, Dq, Dq);
  // x1 = LN1(y1) -> fp32 + bf16
  k_ln<true><<<M, 64, 0, stream>>>(y1, ln1_g, ln1_b, x1f, x1b);
  // h = gelu(x1 @ w1 + b1)
  k_gemm<true, false, true, false><<<dim3(Hq / 128, M / 128), 256, 0, stream>>>(
      x1b, w1T, b1, nullptr, hb, nullptr, M, Hq, Dq);
  // y2 = h @ w2 + b2 + x1
  k_gemm<false, true, false, false><<<dim3(Dq / 128, M / 128), 256, 0, stream>>>(
      hb, w2T, b2, x1f, y1, nullptr, M, Dq, Hq);
  // out = LN2(y2)
  k_ln<false><<<M, 64, 0, stream>>>(y1, ln2_g, ln2_b, out, nullptr);
}